// Round 1
// baseline (91.598 us; speedup 1.0000x reference)
//
#include <hip/hip_runtime.h>
#include <stdint.h>

typedef __attribute__((ext_vector_type(8))) short bf16x8;
typedef __attribute__((ext_vector_type(4))) float f32x4;
typedef unsigned short u16;

__device__ inline u16 f2bf(float f) {
  uint32_t u = __builtin_bit_cast(uint32_t, f);
  uint32_t r = (u + 0x7FFFu + ((u >> 16) & 1u)) >> 16;
  return (u16)r;
}
__device__ inline float bf2f(u16 h) {
  uint32_t u = ((uint32_t)h) << 16;
  return __builtin_bit_cast(float, u);
}

__device__ inline void gload_lds16(const void* g, void* l) {
  __builtin_amdgcn_global_load_lds(
      (const __attribute__((address_space(1))) uint32_t*)g,
      (__attribute__((address_space(3))) uint32_t*)l,
      16, 0, 0);
}

// ---------------- K1: d[b,i] = rsqrt(1 + sum_j adj[b,i,j]) ----------------
__global__ __launch_bounds__(256) void k_rowsum(const float* __restrict__ adj,
                                                float* __restrict__ d) {
  int row = blockIdx.x;  // b*2048 + i, 16384 rows
  const float4* p = (const float4*)(adj + (size_t)row * 2048);
  float s = 0.f;
#pragma unroll
  for (int c = 0; c < 2; ++c) {
    float4 v = p[threadIdx.x + 256 * c];
    s += v.x + v.y + v.z + v.w;
  }
#pragma unroll
  for (int off = 32; off > 0; off >>= 1) s += __shfl_down(s, off, 64);
  __shared__ float red[4];
  int lane = threadIdx.x & 63, w = threadIdx.x >> 6;
  if (lane == 0) red[w] = s;
  __syncthreads();
  if (threadIdx.x == 0) {
    float t = red[0] + red[1] + red[2] + red[3] + 1.0f;  // +I diagonal
    d[row] = 1.0f / sqrtf(t);
  }
}

// ---------------- Wconv: W fp32 -> bf16 (layout [o][f] kept) ----------------
__global__ __launch_bounds__(256) void k_wconv(const float* __restrict__ W,
                                               u16* __restrict__ Wb) {
  int i = blockIdx.x * 256 + threadIdx.x;  // float4 index, 16384 total
  float4 v = ((const float4*)W)[i];
  ushort4 o;
  o.x = f2bf(v.x); o.y = f2bf(v.y); o.z = f2bf(v.z); o.w = f2bf(v.w);
  *(ushort4*)(Wb + (size_t)i * 4) = o;
}

// ---------------- K2: Xp[b,j,f]=bf16(d_j*X), XpT[b,f,j] transposed copy -----
__global__ __launch_bounds__(256) void k_xprep(const float* __restrict__ X,
                                               const float* __restrict__ d,
                                               u16* __restrict__ Xp,
                                               u16* __restrict__ XpT) {
  int jt = blockIdx.x, ft = blockIdx.y, b = blockIdx.z;
  int j0 = jt * 64, f0 = ft * 64;
  __shared__ u16 T[64][66];  // padded to dodge bank conflicts on transpose
  int t = threadIdx.x;
#pragma unroll
  for (int s = 0; s < 4; ++s) {
    int q = s * 256 + t;   // 0..1023
    int r = q >> 4;        // j-row in tile
    int c4 = q & 15;       // float4 along f
    int j = j0 + r;
    float dv = d[b * 2048 + j];
    float4 v = *(const float4*)(X + ((size_t)(b * 2048 + j)) * 256 + f0 + c4 * 4);
    ushort4 o;
    o.x = f2bf(v.x * dv); o.y = f2bf(v.y * dv);
    o.z = f2bf(v.z * dv); o.w = f2bf(v.w * dv);
    *(ushort4*)(Xp + ((size_t)(b * 2048 + j)) * 256 + f0 + c4 * 4) = o;
    T[r][c4 * 4 + 0] = o.x; T[r][c4 * 4 + 1] = o.y;
    T[r][c4 * 4 + 2] = o.z; T[r][c4 * 4 + 3] = o.w;
  }
  __syncthreads();
#pragma unroll
  for (int s = 0; s < 4; ++s) {
    int q = s * 256 + t;
    int fr = q >> 4;   // f-row of transposed tile
    int c4 = q & 15;   // 4-elem chunk along j
    ushort4 o;
    o.x = T[c4 * 4 + 0][fr]; o.y = T[c4 * 4 + 1][fr];
    o.z = T[c4 * 4 + 2][fr]; o.w = T[c4 * 4 + 3][fr];
    *(ushort4*)(XpT + ((size_t)(b * 256 + f0 + fr)) * 2048 + j0 + c4 * 4) = o;
  }
}

// ---------------- GEMM1: H[b] = rowscale_d( adj[b] @ Xp[b] + Xp[b] ) --------
// BM=64, BN=128, BK=32, 4 waves (each 32x64), K=2048
__global__ __launch_bounds__(256, 2) void k_gemm1(const float* __restrict__ adj,
                                                  const u16* __restrict__ XpT,
                                                  const u16* __restrict__ Xp,
                                                  const float* __restrict__ d,
                                                  u16* __restrict__ H) {
  int mt = blockIdx.x, nt = blockIdx.y, b = blockIdx.z;
  int i0 = mt * 64, f0 = nt * 128;
  __shared__ __align__(16) u16 As[64 * 32];
  __shared__ __align__(16) u16 Bs[128 * 32];
  int t = threadIdx.x;
  int lane = t & 63, w = t >> 6;
  int wr = w >> 1, wc = w & 1;
  int l15 = lane & 15, l4 = lane >> 4;

  const float* adjb = adj + (size_t)b * 2048 * 2048;
  const u16* XpTb = XpT + (size_t)b * 256 * 2048;

  f32x4 acc[2][4] = {};

  for (int k0 = 0; k0 < 2048; k0 += 32) {
    // stage A: 64x32 fp32 -> bf16 (reg path, converts on the fly)
#pragma unroll
    for (int s = 0; s < 2; ++s) {
      int q = s * 256 + t;  // float4 index 0..511
      int r = q >> 3, c4 = q & 7;
      float4 v = *(const float4*)(adjb + (size_t)(i0 + r) * 2048 + k0 + c4 * 4);
      ushort4 o;
      o.x = f2bf(v.x); o.y = f2bf(v.y); o.z = f2bf(v.z); o.w = f2bf(v.w);
      *(ushort4*)(&As[r * 32 + c4 * 4]) = o;
    }
    // stage B: 128x32 bf16 from XpT rows, direct-to-LDS, 16B/lane
#pragma unroll
    for (int c = 0; c < 2; ++c) {
      int q = c * 256 + t;  // 16B-chunk 0..511
      int n = q >> 2, slot = q & 3;
      const u16* src = XpTb + (size_t)(f0 + n) * 2048 + k0 + slot * 8;
      u16* dst = Bs + (size_t)(c * 256 + w * 64) * 8;  // wave-uniform base
      gload_lds16(src, dst);
    }
    __syncthreads();

    bf16x8 a[2], bb[4];
#pragma unroll
    for (int mi = 0; mi < 2; ++mi)
      a[mi] = *(const bf16x8*)&As[(wr * 32 + mi * 16 + l15) * 32 + l4 * 8];
#pragma unroll
    for (int ni = 0; ni < 4; ++ni)
      bb[ni] = *(const bf16x8*)&Bs[(wc * 64 + ni * 16 + l15) * 32 + l4 * 8];
#pragma unroll
    for (int mi = 0; mi < 2; ++mi)
#pragma unroll
      for (int ni = 0; ni < 4; ++ni)
        acc[mi][ni] = __builtin_amdgcn_mfma_f32_16x16x32_bf16(a[mi], bb[ni],
                                                              acc[mi][ni], 0, 0, 0);
    __syncthreads();
  }

  const u16* Xpb = Xp + (size_t)b * 2048 * 256;
  const float* db = d + b * 2048;
  u16* Hb = H + (size_t)b * 2048 * 256;
#pragma unroll
  for (int mi = 0; mi < 2; ++mi) {
#pragma unroll
    for (int qq = 0; qq < 4; ++qq) {
      int i = i0 + wr * 32 + mi * 16 + l4 * 4 + qq;
      float dv = db[i];
#pragma unroll
      for (int ni = 0; ni < 4; ++ni) {
        int f = f0 + wc * 64 + ni * 16 + l15;
        float hv = dv * (acc[mi][ni][qq] + bf2f(Xpb[(size_t)i * 256 + f]));
        Hb[(size_t)i * 256 + f] = f2bf(hv);
      }
    }
  }
}

// ---------------- GEMM2: out = relu(H @ W^T + b) ----------------------------
// BM=64, BN=256 (4 waves x 64 cols), K=256
__global__ __launch_bounds__(256, 2) void k_gemm2(const u16* __restrict__ H,
                                                  const u16* __restrict__ Wb,
                                                  const float* __restrict__ bias,
                                                  float* __restrict__ out) {
  int m0 = blockIdx.x * 64;
  __shared__ __align__(16) u16 Hs[64 * 32];
  __shared__ __align__(16) u16 Ws2[256 * 32];
  int t = threadIdx.x, lane = t & 63, w = t >> 6;
  int l15 = lane & 15, l4 = lane >> 4;
  f32x4 acc[4][4] = {};

  for (int k0 = 0; k0 < 256; k0 += 32) {
    {  // Hs: 64x32 = 256 chunks, 1 call
      int q = t, r = q >> 2, slot = q & 3;
      const u16* src = H + (size_t)(m0 + r) * 256 + k0 + slot * 8;
      u16* dst = Hs + (size_t)(w * 64) * 8;
      gload_lds16(src, dst);
    }
#pragma unroll
    for (int c = 0; c < 4; ++c) {  // Ws2: 256x32 = 1024 chunks
      int q = c * 256 + t, r = q >> 2, slot = q & 3;
      const u16* src = Wb + (size_t)r * 256 + k0 + slot * 8;
      u16* dst = Ws2 + (size_t)(c * 256 + w * 64) * 8;
      gload_lds16(src, dst);
    }
    __syncthreads();

    bf16x8 a[4], bb[4];
#pragma unroll
    for (int mi = 0; mi < 4; ++mi)
      a[mi] = *(const bf16x8*)&Hs[(mi * 16 + l15) * 32 + l4 * 8];
#pragma unroll
    for (int ni = 0; ni < 4; ++ni)
      bb[ni] = *(const bf16x8*)&Ws2[(w * 64 + ni * 16 + l15) * 32 + l4 * 8];
#pragma unroll
    for (int mi = 0; mi < 4; ++mi)
#pragma unroll
      for (int ni = 0; ni < 4; ++ni)
        acc[mi][ni] = __builtin_amdgcn_mfma_f32_16x16x32_bf16(a[mi], bb[ni],
                                                              acc[mi][ni], 0, 0, 0);
    __syncthreads();
  }

#pragma unroll
  for (int mi = 0; mi < 4; ++mi) {
#pragma unroll
    for (int qq = 0; qq < 4; ++qq) {
      int i = m0 + mi * 16 + l4 * 4 + qq;
#pragma unroll
      for (int ni = 0; ni < 4; ++ni) {
        int o = w * 64 + ni * 16 + l15;
        float v = acc[mi][ni][qq] + bias[o];
        out[(size_t)i * 256 + o] = fmaxf(v, 0.f);
      }
    }
  }
}

extern "C" void kernel_launch(void* const* d_in, const int* in_sizes, int n_in,
                              void* d_out, int out_size, void* d_ws, size_t ws_size,
                              hipStream_t stream) {
  const float* X    = (const float*)d_in[0];
  const float* adj  = (const float*)d_in[1];
  const float* W    = (const float*)d_in[2];
  const float* bias = (const float*)d_in[3];
  float* out = (float*)d_out;

  char* ws = (char*)d_ws;
  float* dsc = (float*)(ws);                                  // 64 KB
  u16*   Wb  = (u16*)(ws + 65536);                            // 128 KB
  u16*   Xp  = (u16*)(ws + 196608);                           // 8 MB
  u16*   XpT = (u16*)(ws + 196608 + 8388608);                 // 8 MB
  u16*   H   = (u16*)(ws + 196608 + 2 * 8388608);             // 8 MB

  k_rowsum<<<dim3(16384), dim3(256), 0, stream>>>(adj, dsc);
  k_wconv<<<dim3(64), dim3(256), 0, stream>>>(W, Wb);
  k_xprep<<<dim3(32, 4, 8), dim3(256), 0, stream>>>(X, dsc, Xp, XpT);
  k_gemm1<<<dim3(32, 2, 8), dim3(256), 0, stream>>>(adj, XpT, Xp, dsc, H);
  k_gemm2<<<dim3(256), dim3(256), 0, stream>>>(H, Wb, bias, out);
}